// Round 1
// baseline (966.761 us; speedup 1.0000x reference)
//
#include <hip/hip_runtime.h>

// GraphConvolution: out = segment_sum_dst( w_e * (x @ W)[src_e] )
// N=100000 nodes, E=3200000 edges, D_IN=256, D_OUT=128, fp32.

#define DIN 256
#define DOUT 128

struct alignas(8) EdgeRec { int src; float w; };

// ---------------- GEMM: support = x @ W  (fp32 vector ALU) ----------------
// BM=64, BN=128, BK=32. blockDim=256 arranged 16x16, strided 4x8 micro-tile.
__global__ __launch_bounds__(256) void gemm_kernel(const float* __restrict__ x,
                                                   const float* __restrict__ W,
                                                   float* __restrict__ support,
                                                   int M) {
  __shared__ float As[64][33];    // +1 pad: conflict-free a-frag reads
  __shared__ float Bs[32][132];   // +4 pad, keeps float4 store alignment
  const int tid = threadIdx.x;
  const int ty = tid >> 4;        // 0..15 (row group)
  const int tx = tid & 15;        // 0..15 (col group)
  const int rowBase = blockIdx.x * 64;

  float acc[4][8];
#pragma unroll
  for (int i = 0; i < 4; i++)
#pragma unroll
    for (int j = 0; j < 8; j++) acc[i][j] = 0.f;

  for (int k0 = 0; k0 < DIN; k0 += 32) {
    // Stage A tile: 64x32 floats = 512 float4, 2 per thread
#pragma unroll
    for (int l = 0; l < 2; l++) {
      int f = tid + l * 256;
      int r = f >> 3;           // 0..63
      int c4 = f & 7;           // 0..7  -> cols c4*4..+3
      float4 v = make_float4(0.f, 0.f, 0.f, 0.f);
      int gr = rowBase + r;
      if (gr < M) v = *(const float4*)&x[(size_t)gr * DIN + k0 + c4 * 4];
      As[r][c4 * 4 + 0] = v.x;
      As[r][c4 * 4 + 1] = v.y;
      As[r][c4 * 4 + 2] = v.z;
      As[r][c4 * 4 + 3] = v.w;
    }
    // Stage B tile: 32x128 floats = 1024 float4, 4 per thread
#pragma unroll
    for (int l = 0; l < 4; l++) {
      int f = tid + l * 256;
      int r = f >> 5;           // 0..31
      int c4 = f & 31;          // 0..31 -> cols c4*4..+3
      float4 v = *(const float4*)&W[(size_t)(k0 + r) * DOUT + c4 * 4];
      *(float4*)&Bs[r][c4 * 4] = v;
    }
    __syncthreads();
#pragma unroll
    for (int kk = 0; kk < 32; kk++) {
      float a[4], b[8];
#pragma unroll
      for (int i = 0; i < 4; i++) a[i] = As[ty + i * 16][kk];
#pragma unroll
      for (int j = 0; j < 8; j++) b[j] = Bs[kk][tx + j * 16];
#pragma unroll
      for (int i = 0; i < 4; i++)
#pragma unroll
        for (int j = 0; j < 8; j++) acc[i][j] += a[i] * b[j];
    }
    __syncthreads();
  }
#pragma unroll
  for (int i = 0; i < 4; i++) {
    int gr = rowBase + ty + i * 16;
    if (gr < M) {
#pragma unroll
      for (int j = 0; j < 8; j++)
        support[(size_t)gr * DOUT + tx + j * 16] = acc[i][j];
    }
  }
}

// ---------------- CSR build ----------------
__global__ void hist_kernel(const int* __restrict__ dst, int E, int* __restrict__ deg) {
  int i = blockIdx.x * blockDim.x + threadIdx.x;
  if (i < E) atomicAdd(&deg[dst[i]], 1);
}

// per-block (1024 elems) exclusive scan into tmp, block totals into partials
__global__ __launch_bounds__(256) void scan1_kernel(const int* __restrict__ deg, int N,
                                                    int* __restrict__ tmp,
                                                    int* __restrict__ partials) {
  __shared__ int s[256];
  int t = threadIdx.x;
  int base = blockIdx.x * 1024 + t * 4;
  int d0 = 0, d1 = 0, d2 = 0, d3 = 0;
  if (base + 0 < N) d0 = deg[base + 0];
  if (base + 1 < N) d1 = deg[base + 1];
  if (base + 2 < N) d2 = deg[base + 2];
  if (base + 3 < N) d3 = deg[base + 3];
  int tsum = d0 + d1 + d2 + d3;
  s[t] = tsum;
  __syncthreads();
  for (int off = 1; off < 256; off <<= 1) {
    int v = (t >= off) ? s[t - off] : 0;
    __syncthreads();
    s[t] += v;
    __syncthreads();
  }
  int excl = s[t] - tsum;
  if (base + 0 < N) tmp[base + 0] = excl;
  excl += d0;
  if (base + 1 < N) tmp[base + 1] = excl;
  excl += d1;
  if (base + 2 < N) tmp[base + 2] = excl;
  excl += d2;
  if (base + 3 < N) tmp[base + 3] = excl;
  if (t == 255) partials[blockIdx.x] = s[255];
}

// exclusive scan of <=128 block totals, in place
__global__ __launch_bounds__(128) void scan2_kernel(int* __restrict__ partials, int nb) {
  __shared__ int s[128];
  int t = threadIdx.x;
  int v = (t < nb) ? partials[t] : 0;
  s[t] = v;
  __syncthreads();
  for (int off = 1; off < 128; off <<= 1) {
    int u = (t >= off) ? s[t - off] : 0;
    __syncthreads();
    s[t] += u;
    __syncthreads();
  }
  if (t < nb) partials[t] = s[t] - v;
}

__global__ void scan3_kernel(const int* __restrict__ tmp, const int* __restrict__ partials,
                             int N, int E, int* __restrict__ row_ptr,
                             int* __restrict__ cursor) {
  int i = blockIdx.x * blockDim.x + threadIdx.x;
  if (i < N) {
    int v = tmp[i] + partials[i >> 10];
    row_ptr[i] = v;
    cursor[i] = v;
  }
  if (i == 0) row_ptr[N] = E;
}

__global__ void fill_kernel(const int* __restrict__ src, const int* __restrict__ dst,
                            const float* __restrict__ w, int E,
                            int* __restrict__ cursor, EdgeRec* __restrict__ csr) {
  int e = blockIdx.x * blockDim.x + threadIdx.x;
  if (e < E) {
    int d = dst[e];
    int pos = atomicAdd(&cursor[d], 1);
    EdgeRec r;
    r.src = src[e];
    r.w = w[e];
    csr[pos] = r;
  }
}

// ---------------- gather SpMM: one wave per destination node ----------------
__global__ __launch_bounds__(256) void spmm_kernel(const float* __restrict__ support,
                                                   const int* __restrict__ row_ptr,
                                                   const EdgeRec* __restrict__ csr,
                                                   float* __restrict__ out, int N) {
  int wave = threadIdx.x >> 6;
  int lane = threadIdx.x & 63;
  int node = blockIdx.x * 4 + wave;
  if (node >= N) return;
  int j0 = row_ptr[node];
  int j1 = row_ptr[node + 1];
  float2 acc = make_float2(0.f, 0.f);
  const float2* sup2 = (const float2*)support;
  for (int j = j0; j < j1; j++) {
    EdgeRec r = csr[j];
    float2 v = sup2[(size_t)r.src * 64 + lane];
    acc.x += r.w * v.x;
    acc.y += r.w * v.y;
  }
  ((float2*)out)[(size_t)node * 64 + lane] = acc;
}

// ---------------- fallback: atomic scatter (small ws) ----------------
__global__ void scatter_kernel(const float* __restrict__ support,
                               const int* __restrict__ src, const int* __restrict__ dst,
                               const float* __restrict__ w, long long total,
                               float* __restrict__ out) {
  long long i = (long long)blockIdx.x * blockDim.x + threadIdx.x;
  if (i < total) {
    int e = (int)(i >> 7);
    int c = (int)(i & 127);
    atomicAdd(&out[(size_t)dst[e] * DOUT + c], w[e] * support[(size_t)src[e] * DOUT + c]);
  }
}

extern "C" void kernel_launch(void* const* d_in, const int* in_sizes, int n_in,
                              void* d_out, int out_size, void* d_ws, size_t ws_size,
                              hipStream_t stream) {
  const float* x = (const float*)d_in[0];
  const int* esrc = (const int*)d_in[1];
  const int* edst = (const int*)d_in[2];
  const float* ew = (const float*)d_in[3];
  const float* W = (const float*)d_in[4];
  float* out = (float*)d_out;

  const int N = in_sizes[0] / DIN;   // 100000
  const int E = in_sizes[1];         // 3200000

  char* ws = (char*)d_ws;
  size_t off = 0;
  auto alloc = [&](size_t bytes) {
    size_t o = off;
    off = (off + bytes + 255) & ~(size_t)255;
    return o;
  };
  size_t sup_off = alloc((size_t)N * DOUT * 4);
  size_t rp_off = alloc((size_t)(N + 1) * 4);
  size_t deg_off = alloc((size_t)N * 4);
  size_t cur_off = alloc((size_t)N * 4);
  size_t tmp_off = alloc((size_t)N * 4);
  size_t part_off = alloc(128 * 4);
  size_t csr_off = alloc((size_t)E * sizeof(EdgeRec));
  bool use_csr = (off <= ws_size);

  float* support = (float*)(ws + sup_off);
  int* row_ptr = (int*)(ws + rp_off);
  int* deg = (int*)(ws + deg_off);
  int* cursor = (int*)(ws + cur_off);
  int* tmp = (int*)(ws + tmp_off);
  int* partials = (int*)(ws + part_off);
  EdgeRec* csr = (EdgeRec*)(ws + csr_off);

  // 1) GEMM
  gemm_kernel<<<(N + 63) / 64, 256, 0, stream>>>(x, W, support, N);

  if (use_csr) {
    // 2) CSR build by destination
    hipMemsetAsync(deg, 0, (size_t)N * 4, stream);
    hist_kernel<<<(E + 255) / 256, 256, 0, stream>>>(edst, E, deg);
    int nb = (N + 1023) / 1024;   // 98 <= 128
    scan1_kernel<<<nb, 256, 0, stream>>>(deg, N, tmp, partials);
    scan2_kernel<<<1, 128, 0, stream>>>(partials, nb);
    scan3_kernel<<<(N + 255) / 256, 256, 0, stream>>>(tmp, partials, N, E, row_ptr, cursor);
    fill_kernel<<<(E + 255) / 256, 256, 0, stream>>>(esrc, edst, ew, E, cursor, csr);
    // 3) gather SpMM (one wave per node, float2 per lane over 128 cols)
    spmm_kernel<<<(N + 3) / 4, 256, 0, stream>>>(support, row_ptr, csr, out, N);
  } else {
    // fallback: atomic scatter
    hipMemsetAsync(out, 0, (size_t)N * DOUT * 4, stream);
    long long total = (long long)E * DOUT;
    scatter_kernel<<<(int)((total + 255) / 256), 256, 0, stream>>>(support, esrc, edst, ew,
                                                                   total, out);
  }
}

// Round 2
// 742.995 us; speedup vs baseline: 1.3012x; 1.3012x over previous
//
#include <hip/hip_runtime.h>

// GraphConvolution: out = segment_sum_dst( w_e * (x @ W)[src_e] )
// N=100000 nodes, E=3200000 edges, D_IN=256, D_OUT=128, fp32 in/out.
// support table stored as packed bf16x2 to halve gather traffic.

#define DIN 256
#define DOUT 128

struct alignas(8) EdgeRec { int src; float w; };

__device__ __forceinline__ unsigned pack_bf16x2(float a, float b) {
  unsigned ua = __float_as_uint(a);
  unsigned ub = __float_as_uint(b);
  ua += 0x7fffu + ((ua >> 16) & 1u);   // round-to-nearest-even
  ub += 0x7fffu + ((ub >> 16) & 1u);
  return (ua >> 16) | (ub & 0xffff0000u);
}
__device__ __forceinline__ float bf_lo(unsigned p) { return __uint_as_float(p << 16); }
__device__ __forceinline__ float bf_hi(unsigned p) { return __uint_as_float(p & 0xffff0000u); }

// ---------------- GEMM: support = x @ W (fp32 vector ALU, bf16x2 output) ---
// BM=64, BN=128, BK=32. blockDim=256 arranged 16x16; thread owns 4 rows x
// (4 col-pairs) so the epilogue can pack adjacent cols into one bf16x2 uint.
__global__ __launch_bounds__(256) void gemm_kernel(const float* __restrict__ x,
                                                   const float* __restrict__ W,
                                                   unsigned* __restrict__ support,
                                                   int M) {
  __shared__ float As[64][33];
  __shared__ float Bs[32][132];
  const int tid = threadIdx.x;
  const int ty = tid >> 4;        // 0..15 row group
  const int tx = tid & 15;        // 0..15 col-pair group
  const int rowBase = blockIdx.x * 64;

  float acc[4][8];                // [row i][pair jj*2 + parity]
#pragma unroll
  for (int i = 0; i < 4; i++)
#pragma unroll
    for (int j = 0; j < 8; j++) acc[i][j] = 0.f;

  for (int k0 = 0; k0 < DIN; k0 += 32) {
#pragma unroll
    for (int l = 0; l < 2; l++) {
      int f = tid + l * 256;
      int r = f >> 3, c4 = f & 7;
      float4 v = make_float4(0.f, 0.f, 0.f, 0.f);
      int gr = rowBase + r;
      if (gr < M) v = *(const float4*)&x[(size_t)gr * DIN + k0 + c4 * 4];
      As[r][c4 * 4 + 0] = v.x; As[r][c4 * 4 + 1] = v.y;
      As[r][c4 * 4 + 2] = v.z; As[r][c4 * 4 + 3] = v.w;
    }
#pragma unroll
    for (int l = 0; l < 4; l++) {
      int f = tid + l * 256;
      int r = f >> 5, c4 = f & 31;
      float4 v = *(const float4*)&W[(size_t)(k0 + r) * DOUT + c4 * 4];
      *(float4*)&Bs[r][c4 * 4] = v;
    }
    __syncthreads();
#pragma unroll
    for (int kk = 0; kk < 32; kk++) {
      float a[4];
#pragma unroll
      for (int i = 0; i < 4; i++) a[i] = As[ty + i * 16][kk];
      float b[8];
#pragma unroll
      for (int jj = 0; jj < 4; jj++) {
        float2 bb = *(const float2*)&Bs[kk][32 * jj + 2 * tx];
        b[2 * jj] = bb.x; b[2 * jj + 1] = bb.y;
      }
#pragma unroll
      for (int i = 0; i < 4; i++)
#pragma unroll
        for (int j = 0; j < 8; j++) acc[i][j] += a[i] * b[j];
    }
    __syncthreads();
  }
#pragma unroll
  for (int i = 0; i < 4; i++) {
    int gr = rowBase + ty + i * 16;
    if (gr < M) {
#pragma unroll
      for (int jj = 0; jj < 4; jj++)
        support[(size_t)gr * 64 + 16 * jj + tx] =
            pack_bf16x2(acc[i][2 * jj], acc[i][2 * jj + 1]);
    }
  }
}

// ---------------- CSR build ----------------
__global__ void hist_kernel(const int* __restrict__ dst, int E, int* __restrict__ deg) {
  int i = blockIdx.x * blockDim.x + threadIdx.x;
  if (i < E) atomicAdd(&deg[dst[i]], 1);
}

__global__ __launch_bounds__(256) void scan1_kernel(const int* __restrict__ deg, int N,
                                                    int* __restrict__ tmp,
                                                    int* __restrict__ partials) {
  __shared__ int s[256];
  int t = threadIdx.x;
  int base = blockIdx.x * 1024 + t * 4;
  int d0 = 0, d1 = 0, d2 = 0, d3 = 0;
  if (base + 0 < N) d0 = deg[base + 0];
  if (base + 1 < N) d1 = deg[base + 1];
  if (base + 2 < N) d2 = deg[base + 2];
  if (base + 3 < N) d3 = deg[base + 3];
  int tsum = d0 + d1 + d2 + d3;
  s[t] = tsum;
  __syncthreads();
  for (int off = 1; off < 256; off <<= 1) {
    int v = (t >= off) ? s[t - off] : 0;
    __syncthreads();
    s[t] += v;
    __syncthreads();
  }
  int excl = s[t] - tsum;
  if (base + 0 < N) tmp[base + 0] = excl;
  excl += d0;
  if (base + 1 < N) tmp[base + 1] = excl;
  excl += d1;
  if (base + 2 < N) tmp[base + 2] = excl;
  excl += d2;
  if (base + 3 < N) tmp[base + 3] = excl;
  if (t == 255) partials[blockIdx.x] = s[255];
}

__global__ __launch_bounds__(128) void scan2_kernel(int* __restrict__ partials, int nb) {
  __shared__ int s[128];
  int t = threadIdx.x;
  int v = (t < nb) ? partials[t] : 0;
  s[t] = v;
  __syncthreads();
  for (int off = 1; off < 128; off <<= 1) {
    int u = (t >= off) ? s[t - off] : 0;
    __syncthreads();
    s[t] += u;
    __syncthreads();
  }
  if (t < nb) partials[t] = s[t] - v;
}

__global__ void scan3_kernel(const int* __restrict__ tmp, const int* __restrict__ partials,
                             int N, int E, int* __restrict__ row_ptr,
                             int* __restrict__ cursor) {
  int i = blockIdx.x * blockDim.x + threadIdx.x;
  if (i < N) {
    int v = tmp[i] + partials[i >> 10];
    row_ptr[i] = v;
    cursor[i] = v;
  }
  if (i == 0) row_ptr[N] = E;
}

__global__ void fill_kernel(const int* __restrict__ src, const int* __restrict__ dst,
                            const float* __restrict__ w, int E,
                            int* __restrict__ cursor, EdgeRec* __restrict__ csr) {
  int e = blockIdx.x * blockDim.x + threadIdx.x;
  if (e < E) {
    int d = dst[e];
    int pos = atomicAdd(&cursor[d], 1);
    EdgeRec r; r.src = src[e]; r.w = w[e];
    csr[pos] = r;
  }
}

// ---------------- gather SpMM: one wave per destination node ---------------
// Edge records loaded cooperatively (one per lane per 64-chunk), broadcast
// via v_readlane; 8 independent row-gathers in flight per unrolled step.
__global__ __launch_bounds__(256) void spmm_kernel(const unsigned* __restrict__ sup,
                                                   const int* __restrict__ row_ptr,
                                                   const EdgeRec* __restrict__ csr,
                                                   float* __restrict__ out, int N) {
  int wave = threadIdx.x >> 6;
  int lane = threadIdx.x & 63;
  int node = blockIdx.x * 4 + wave;
  if (node >= N) return;
  int j0 = row_ptr[node];
  int j1 = row_ptr[node + 1];
  float accx = 0.f, accy = 0.f;
  for (int base = j0; base < j1; base += 64) {
    int cnt = min(64, j1 - base);
    int mysrc = 0, myw = 0;
    if (lane < cnt) {
      EdgeRec r = csr[base + lane];
      mysrc = r.src;
      myw = __float_as_int(r.w);
    }
    int j = 0;
    for (; j + 8 <= cnt; j += 8) {
      int s[8]; float w[8]; unsigned p[8];
#pragma unroll
      for (int u = 0; u < 8; u++) {
        s[u] = __builtin_amdgcn_readlane(mysrc, j + u);
        w[u] = __int_as_float(__builtin_amdgcn_readlane(myw, j + u));
      }
#pragma unroll
      for (int u = 0; u < 8; u++) p[u] = sup[(size_t)s[u] * 64 + lane];
#pragma unroll
      for (int u = 0; u < 8; u++) {
        accx += w[u] * bf_lo(p[u]);
        accy += w[u] * bf_hi(p[u]);
      }
    }
    for (; j < cnt; j++) {
      int sj = __builtin_amdgcn_readlane(mysrc, j);
      float wj = __int_as_float(__builtin_amdgcn_readlane(myw, j));
      unsigned pj = sup[(size_t)sj * 64 + lane];
      accx += wj * bf_lo(pj);
      accy += wj * bf_hi(pj);
    }
  }
  ((float2*)out)[(size_t)node * 64 + lane] = make_float2(accx, accy);
}

// ---------------- fallback: atomic scatter (small ws) ----------------
__global__ void scatter_kernel(const float* __restrict__ x, const float* __restrict__ W,
                               const int* __restrict__ src, const int* __restrict__ dst,
                               const float* __restrict__ w, long long total,
                               float* __restrict__ out) {
  long long i = (long long)blockIdx.x * blockDim.x + threadIdx.x;
  if (i < total) {
    int e = (int)(i >> 7);
    int c = (int)(i & 127);
    float acc = 0.f;
    const float* xr = &x[(size_t)src[e] * DIN];
    for (int k = 0; k < DIN; k++) acc += xr[k] * W[(size_t)k * DOUT + c];
    atomicAdd(&out[(size_t)dst[e] * DOUT + c], w[e] * acc);
  }
}

extern "C" void kernel_launch(void* const* d_in, const int* in_sizes, int n_in,
                              void* d_out, int out_size, void* d_ws, size_t ws_size,
                              hipStream_t stream) {
  const float* x = (const float*)d_in[0];
  const int* esrc = (const int*)d_in[1];
  const int* edst = (const int*)d_in[2];
  const float* ew = (const float*)d_in[3];
  const float* W = (const float*)d_in[4];
  float* out = (float*)d_out;

  const int N = in_sizes[0] / DIN;   // 100000
  const int E = in_sizes[1];         // 3200000

  char* ws = (char*)d_ws;
  size_t off = 0;
  auto alloc = [&](size_t bytes) {
    size_t o = off;
    off = (off + bytes + 255) & ~(size_t)255;
    return o;
  };
  size_t sup_off = alloc((size_t)N * 64 * 4);      // bf16x2 table: N x 64 uints
  size_t rp_off = alloc((size_t)(N + 1) * 4);
  size_t deg_off = alloc((size_t)N * 4);
  size_t cur_off = alloc((size_t)N * 4);
  size_t tmp_off = alloc((size_t)N * 4);
  size_t part_off = alloc(128 * 4);
  size_t csr_off = alloc((size_t)E * sizeof(EdgeRec));
  bool use_csr = (off <= ws_size);

  unsigned* support = (unsigned*)(ws + sup_off);
  int* row_ptr = (int*)(ws + rp_off);
  int* deg = (int*)(ws + deg_off);
  int* cursor = (int*)(ws + cur_off);
  int* tmp = (int*)(ws + tmp_off);
  int* partials = (int*)(ws + part_off);
  EdgeRec* csr = (EdgeRec*)(ws + csr_off);

  if (use_csr) {
    gemm_kernel<<<(N + 63) / 64, 256, 0, stream>>>(x, W, support, N);
    hipMemsetAsync(deg, 0, (size_t)N * 4, stream);
    hist_kernel<<<(E + 255) / 256, 256, 0, stream>>>(edst, E, deg);
    int nb = (N + 1023) / 1024;
    scan1_kernel<<<nb, 256, 0, stream>>>(deg, N, tmp, partials);
    scan2_kernel<<<1, 128, 0, stream>>>(partials, nb);
    scan3_kernel<<<(N + 255) / 256, 256, 0, stream>>>(tmp, partials, N, E, row_ptr, cursor);
    fill_kernel<<<(E + 255) / 256, 256, 0, stream>>>(esrc, edst, ew, E, cursor, csr);
    spmm_kernel<<<(N + 3) / 4, 256, 0, stream>>>(support, row_ptr, csr, out, N);
  } else {
    hipMemsetAsync(out, 0, (size_t)N * DOUT * 4, stream);
    long long total = (long long)E * DOUT;
    scatter_kernel<<<(int)((total + 255) / 256), 256, 0, stream>>>(x, W, esrc, edst, ew,
                                                                   total, out);
  }
}